// Round 5
// baseline (3630.008 us; speedup 1.0000x reference)
//
#include <hip/hip_runtime.h>

#define LL 4096
#define DMODEL 1024
#define DINNER 2048
#define NHEADS 32
#define DSTATE 128
#define DINPROJ 4384
#define NPROJ 4416         // 69*64: padded column count of zxb f32 buffer
#define CONVDIM 2304
#define ROWS 8192
#define CL 1024            // rows per L-chunk
#define CRO 1088           // 17*64 rows computed by gemm1 per chunk (needs CL+3)

__device__ __forceinline__ float bf2f(ushort u){ union{uint i;float f;} v; v.i=(uint)u<<16; return v.f; }

// dtype-dispatched loads: bf=1 -> bf16 source, bf=0 -> f32 source
__device__ __forceinline__ float ldf(const void* p, long i, int bf){
  return bf ? bf2f(((const ushort*)p)[i]) : ((const float*)p)[i];
}
__device__ __forceinline__ float4 ldf4(const void* p, long i, int bf){
  if (bf){ ushort4 u = *(const ushort4*)((const ushort*)p + i);
           return make_float4(bf2f(u.x),bf2f(u.y),bf2f(u.z),bf2f(u.w)); }
  return *(const float4*)((const float*)p + i);
}

// ---- detect input dtype: flag=1 if bf16, 0 if f32 (sample in_proj_w) ----
__global__ __launch_bounds__(256) void detect_k(const ushort* __restrict__ w, int* flag){
  int t = threadIdx.x;
  int c = 0;
  #pragma unroll
  for (int i=0;i<16;i++){
    ushort u = w[(t*16 + i)*2];
    int e = (u >> 7) & 0xff;
    c += (e >= 0x60 && e <= 0x9f) ? 1 : 0;
  }
  #pragma unroll
  for (int m=1;m<64;m<<=1) c += __shfl_xor(c, m);
  __shared__ int red[4];
  if ((t & 63) == 0) red[t>>6] = c;
  __syncthreads();
  if (t == 0) *flag = ((red[0]+red[1]+red[2]+red[3]) > 3072) ? 1 : 0;
}

// ---- fp32 GEMM: C[m,n] = A[clamp(grow0+m)][:K] . W[n][:K]  (W row>=wrows -> 0)
// 64x64 tile, 256 thr, 4x4 micro, k-step 16, LDS transposed [k][m]/[k][n]
__global__ __launch_bounds__(256) void gemm_f32(
    const void* __restrict__ A, int lda, long grow0, long rowmax, int adisp,
    const void* __restrict__ W, int wrows,
    float* __restrict__ C, int ldc, int K,
    const int* __restrict__ flag){
  __shared__ float Ak[16][68];
  __shared__ float Wk[16][68];
  const int t = threadIdx.x;
  const int tx = t & 15, ty = t >> 4;
  const int m0 = blockIdx.y*64, n0 = blockIdx.x*64;
  const int r = t >> 2, kq = (t & 3) * 4;
  const int fb = *flag;
  const int abf = adisp ? fb : 0;
  long ga = grow0 + m0 + r; if (ga < 0) ga = 0; if (ga > rowmax) ga = rowmax;
  const int wr = n0 + r;
  float acc[4][4] = {};
  for (int k0 = 0; k0 < K; k0 += 16){
    float4 av = ldf4(A, ga*(long)lda + k0 + kq, abf);
    float4 wv = (wr < wrows) ? ldf4(W, (long)wr*K + k0 + kq, fb) : make_float4(0.f,0.f,0.f,0.f);
    __syncthreads();
    Ak[kq+0][r]=av.x; Ak[kq+1][r]=av.y; Ak[kq+2][r]=av.z; Ak[kq+3][r]=av.w;
    Wk[kq+0][r]=wv.x; Wk[kq+1][r]=wv.y; Wk[kq+2][r]=wv.z; Wk[kq+3][r]=wv.w;
    __syncthreads();
    #pragma unroll
    for (int kk=0;kk<16;kk++){
      float4 a = *(const float4*)&Ak[kk][ty*4];
      float4 b = *(const float4*)&Wk[kk][tx*4];
      acc[0][0] = fmaf(a.x,b.x,acc[0][0]); acc[0][1] = fmaf(a.x,b.y,acc[0][1]);
      acc[0][2] = fmaf(a.x,b.z,acc[0][2]); acc[0][3] = fmaf(a.x,b.w,acc[0][3]);
      acc[1][0] = fmaf(a.y,b.x,acc[1][0]); acc[1][1] = fmaf(a.y,b.y,acc[1][1]);
      acc[1][2] = fmaf(a.y,b.z,acc[1][2]); acc[1][3] = fmaf(a.y,b.w,acc[1][3]);
      acc[2][0] = fmaf(a.z,b.x,acc[2][0]); acc[2][1] = fmaf(a.z,b.y,acc[2][1]);
      acc[2][2] = fmaf(a.z,b.z,acc[2][2]); acc[2][3] = fmaf(a.z,b.w,acc[2][3]);
      acc[3][0] = fmaf(a.w,b.x,acc[3][0]); acc[3][1] = fmaf(a.w,b.y,acc[3][1]);
      acc[3][2] = fmaf(a.w,b.z,acc[3][2]); acc[3][3] = fmaf(a.w,b.w,acc[3][3]);
    }
  }
  #pragma unroll
  for (int i=0;i<4;i++){
    long row = m0 + ty*4 + i;
    #pragma unroll
    for (int j=0;j<4;j++)
      C[row*(long)ldc + n0 + tx*4 + j] = acc[i][j];
  }
}

// ---- depthwise conv4 + bias + SiLU (f32); seed yb = Dp * x ----
__global__ __launch_bounds__(256) void conv_act_f32(const float* __restrict__ zx,
    const void* __restrict__ cw, const void* __restrict__ cb, const void* __restrict__ Dp,
    float* __restrict__ xconv, float* __restrict__ yb, int l0, const int* __restrict__ flag){
  const int fb = *flag;
  int c = blockIdx.x*256 + threadIdx.x;             // 0..2303
  int by = blockIdx.y;                              // 0..CL-1
  int l = l0 + by;                                  // within-batch position
  float acc = ldf(cb, c, fb);
  #pragma unroll
  for (int j=0;j<4;j++){
    if (l - 3 + j >= 0)
      acc = fmaf(zx[(size_t)(by+j)*NPROJ + DINNER + c], ldf(cw, c*4+j, fb), acc);
  }
  float v = acc / (1.f + expf(-acc));
  xconv[(size_t)by*CONVDIM + c] = v;
  if (c < DINNER) yb[(size_t)by*DINNER + c] = ldf(Dp, c>>6, fb) * v;
}

// ---- dt = softplus(dt_raw + bias); dA = exp(dt * -exp(A_log)) ----
__global__ __launch_bounds__(256) void dt_f32(const float* __restrict__ zx,
    const void* __restrict__ dtb, const void* __restrict__ alog,
    float* __restrict__ dtv, float* __restrict__ dAv, const int* __restrict__ flag){
  const int fb = *flag;
  int i = blockIdx.x*256 + threadIdx.x;             // < CL*32
  int lr = i >> 5, h = i & 31;
  float xv = zx[(size_t)(lr+3)*NPROJ + (DINNER + CONVDIM) + h] + ldf(dtb, h, fb);
  float sp = (xv > 20.f) ? xv : log1pf(expf(xv));
  float A = -expf(ldf(alog, h, fb));
  dtv[i] = sp;
  dAv[i] = expf(sp * A);
}

// ---- selective scan over one chunk (f32); state persists across chunks ----
__global__ __launch_bounds__(256) void scan_f32(const float* __restrict__ xconv,
    const float* __restrict__ dtv, const float* __restrict__ dAv,
    float* __restrict__ yb, float4* __restrict__ hstate, int b, int init){
  const int nb = blockIdx.x, h = blockIdx.y;
  const int tid = threadIdx.x;
  const int p = tid >> 2, q = tid & 3;
  __shared__ float xs[64*64];
  __shared__ float Bsm[64*16];
  __shared__ float Csm[64*16];
  __shared__ float dts[64], dAs[64];
  const int hidx = ((b*NHEADS + h)*8 + nb)*256 + tid;
  float h0=0.f,h1=0.f,h2=0.f,h3=0.f;
  if (!init){ float4 hs = hstate[hidx]; h0=hs.x; h1=hs.y; h2=hs.z; h3=hs.w; }
  for (int c0 = 0; c0 < CL; c0 += 64){
    __syncthreads();
    #pragma unroll
    for (int i=0;i<4;i++){
      int v = tid + i*256;
      int r = v >> 4, c4 = v & 15;
      *(float4*)&xs[r*64 + c4*4] =
        *(const float4*)(xconv + (size_t)(c0 + r)*CONVDIM + h*64 + c4*4);
    }
    { int r = tid >> 2, c4 = tid & 3;
      *(float4*)&Bsm[r*16 + c4*4] =
        *(const float4*)(xconv + (size_t)(c0 + r)*CONVDIM + DINNER + nb*16 + c4*4);
      *(float4*)&Csm[r*16 + c4*4] =
        *(const float4*)(xconv + (size_t)(c0 + r)*CONVDIM + DINNER + DSTATE + nb*16 + c4*4);
    }
    if (tid < 64) dts[tid] = dtv[(size_t)(c0 + tid)*NHEADS + h];
    else if (tid < 128) dAs[tid-64] = dAv[(size_t)(c0 + tid - 64)*NHEADS + h];
    __syncthreads();
    #pragma unroll 4
    for (int s=0;s<64;s++){
      float xv = xs[s*64 + p];
      float a  = dts[s] * xv;
      float dA = dAs[s];
      float4 Bv = *(float4*)&Bsm[s*16 + q*4];
      float4 Cv = *(float4*)&Csm[s*16 + q*4];
      h0 = fmaf(h0, dA, Bv.x*a);
      h1 = fmaf(h1, dA, Bv.y*a);
      h2 = fmaf(h2, dA, Bv.z*a);
      h3 = fmaf(h3, dA, Bv.w*a);
      float y = fmaf(h0, Cv.x, fmaf(h1, Cv.y, fmaf(h2, Cv.z, h3*Cv.w)));
      y += __shfl_xor(y, 1);
      y += __shfl_xor(y, 2);
      if (q == 0) atomicAdd(&yb[(size_t)(c0 + s)*DINNER + h*64 + p], y);
    }
  }
  float4 hs; hs.x=h0; hs.y=h1; hs.z=h2; hs.w=h3;
  hstate[hidx] = hs;
}

// ---- y *= silu(z); RMSNorm(2048) * norm_w -> yn (f32) ----
__global__ __launch_bounds__(256) void gate_norm_f32(const float* __restrict__ yb,
    const float* __restrict__ zx, const void* __restrict__ nw,
    float* __restrict__ yn, const int* __restrict__ flag){
  const int fb = *flag;
  int lr = blockIdx.x, tid = threadIdx.x;
  int d0 = tid*8;
  const float* yrow = yb + (size_t)lr*DINNER;
  const float* zrow = zx + (size_t)(lr+3)*NPROJ;
  float y[8]; float ss = 0.f;
  #pragma unroll
  for (int i=0;i<8;i++){
    float z = zrow[d0+i];
    float g = z / (1.f + expf(-z));
    float v = yrow[d0+i] * g;
    y[i] = v; ss += v*v;
  }
  #pragma unroll
  for (int m=1;m<64;m<<=1) ss += __shfl_xor(ss, m);
  __shared__ float red[4];
  if ((tid & 63) == 0) red[tid>>6] = ss;
  __syncthreads();
  ss = red[0]+red[1]+red[2]+red[3];
  float scale = rsqrtf(ss * (1.f/DINNER) + 1e-5f);
  float* out = yn + (size_t)lr*DINNER;
  #pragma unroll
  for (int i=0;i<8;i++)
    out[d0+i] = y[i] * scale * ldf(nw, d0+i, fb);
}

extern "C" void kernel_launch(void* const* d_in, const int* in_sizes, int n_in,
                              void* d_out, int out_size, void* d_ws, size_t ws_size,
                              hipStream_t stream) {
  const void* x    = d_in[0];
  const void* ipw  = d_in[1];
  const void* cw   = d_in[2];
  const void* cb   = d_in[3];
  const void* dtb  = d_in[4];
  const void* alog = d_in[5];
  const void* Dp   = d_in[6];
  const void* nw   = d_in[7];
  const void* opw  = d_in[8];
  char* ws = (char*)d_ws;
  size_t off = 0;
  int*    flag   = (int*)(ws + off);    off += 256;
  float*  zxb    = (float*)(ws + off);  off += (size_t)CRO*NPROJ*4;       // 19.2 MB
  float*  xconv  = (float*)(ws + off);  off += (size_t)CL*CONVDIM*4;      //  9.4 MB
  float*  dtv    = (float*)(ws + off);  off += (size_t)CL*NHEADS*4;       //  0.13 MB
  float*  dAv    = (float*)(ws + off);  off += (size_t)CL*NHEADS*4;       //  0.13 MB
  float*  yb     = (float*)(ws + off);  off += (size_t)CL*DINNER*4;       //  8.4 MB
  float*  yn     = (float*)(ws + off);  off += (size_t)CL*DINNER*4;       //  8.4 MB
  float4* hstate = (float4*)(ws + off); off += (size_t)2*NHEADS*8*256*16; //  2.1 MB
  // total ~47.7 MB

  detect_k<<<1, 256, 0, stream>>>((const ushort*)ipw, flag);

  for (int ck = 0; ck < 8; ck++){
    int b  = ck >> 2;
    int l0 = (ck & 3) * CL;
    long grow0 = (long)b*LL + l0 - 3;
    // zxbcdt chunk: [CRO rows][NPROJ], valid cols 0..4383
    gemm_f32<<<dim3(NPROJ/64, CRO/64), 256, 0, stream>>>(
        x, DMODEL, grow0, (long)ROWS-1, 1, ipw, DINPROJ,
        zxb, NPROJ, DMODEL, flag);
    conv_act_f32<<<dim3(CONVDIM/256, CL), 256, 0, stream>>>(
        zxb, cw, cb, Dp, xconv, yb, l0, flag);
    dt_f32<<<CL*NHEADS/256, 256, 0, stream>>>(zxb, dtb, alog, dtv, dAv, flag);
    scan_f32<<<dim3(8, NHEADS), 256, 0, stream>>>(
        xconv, dtv, dAv, yb, hstate, b, (l0==0)?1:0);
    gate_norm_f32<<<CL, 256, 0, stream>>>(yb, zxb, nw, yn, flag);
    gemm_f32<<<dim3(DMODEL/64, CL/64), 256, 0, stream>>>(
        yn, DINNER, 0, (long)CL-1, 0, opw, DMODEL,
        (float*)d_out + (size_t)(b*LL + l0)*DMODEL, DMODEL, DINNER, flag);
  }
}

// Round 6
// 2192.738 us; speedup vs baseline: 1.6555x; 1.6555x over previous
//
#include <hip/hip_runtime.h>

#define LL 4096
#define DMODEL 1024
#define DINNER 2048
#define NHEADS 32
#define DSTATE 128
#define DINPROJ 4384
#define NPAD 4480          // 35*128 padded gemm1 N; also zxb f32 row stride
#define CONVDIM 2304
#define ROWS 8192
#define CL 1024            // rows per L-chunk
#define CR 1152            // 9*128 rows computed by gemm1 per chunk (CL + 3 halo)

typedef __attribute__((ext_vector_type(8))) __bf16 bf16x8;
typedef __attribute__((ext_vector_type(4))) float f32x4;

__device__ __forceinline__ ushort f2bf(float f){ union{float f;uint i;} v; v.f=f; uint r=v.i+0x7fffu+((v.i>>16)&1u); return (ushort)(r>>16); }

// ---- f32 -> bf16, 8 elems/thread ----
__global__ __launch_bounds__(256) void cvt_k(const float4* __restrict__ src, uint4* __restrict__ dst){
  long t = (long)blockIdx.x*256 + threadIdx.x;
  float4 a = src[t*2], b = src[t*2+1];
  ushort u[8] = { f2bf(a.x),f2bf(a.y),f2bf(a.z),f2bf(a.w),
                  f2bf(b.x),f2bf(b.y),f2bf(b.z),f2bf(b.w) };
  dst[t] = *(uint4*)u;
}

// ---- in_proj_w f32 (4384x1024) -> padded bf16 (4480x1024) ----
__global__ __launch_bounds__(256) void padw_cvt(const float4* __restrict__ W, ushort4* __restrict__ Wp){
  int row = blockIdx.x, c = threadIdx.x;
  ushort4 o = make_ushort4(0,0,0,0);
  if (row < DINPROJ){
    float4 f = W[(size_t)row*256 + c];
    o = make_ushort4(f2bf(f.x), f2bf(f.y), f2bf(f.z), f2bf(f.w));
  }
  Wp[(size_t)row*256 + c] = o;
}

// ---- bf16 MFMA GEMM: C_f32[m,n] = A[clamp(grow0+m)][:K] . W[n][:K]
// 128x128 tile, 256 thr = 4 waves (2x2), wave 64x64 via 4x4 mfma 16x16x32 bf16
__global__ __launch_bounds__(256) void gemm_bt(
    const ushort* __restrict__ A, int lda, long grow0, long rowmax,
    const ushort* __restrict__ W,
    float* __restrict__ C, int ldc, int K){
  __shared__ ushort As[128*40];   // +8 pad: conflict-free b128 frag reads
  __shared__ ushort Bs[128*40];
  const int tid = threadIdx.x;
  const int lane = tid & 63, wave = tid >> 6;
  const int wm = wave >> 1, wn = wave & 1;
  const int m0 = blockIdx.y * 128, n0 = blockIdx.x * 128;
  const int srow = tid >> 2, skc = tid & 3;        // 64 rows x 4 k-chunks of 8 bf16
  const int fr = lane & 15, kq = (lane >> 4) * 8;
  long ga0 = grow0 + m0 + srow;      if (ga0 < 0) ga0 = 0; if (ga0 > rowmax) ga0 = rowmax;
  long ga1 = grow0 + m0 + 64 + srow; if (ga1 < 0) ga1 = 0; if (ga1 > rowmax) ga1 = rowmax;
  f32x4 acc[4][4] = {};
  for (int k0 = 0; k0 < K; k0 += 32){
    uint4 a0 = *(const uint4*)(A + ga0*(long)lda + k0 + skc*8);
    uint4 a1 = *(const uint4*)(A + ga1*(long)lda + k0 + skc*8);
    uint4 b0 = *(const uint4*)(W + (size_t)(n0 + srow)*K      + k0 + skc*8);
    uint4 b1 = *(const uint4*)(W + (size_t)(n0 + 64 + srow)*K + k0 + skc*8);
    __syncthreads();
    *(uint4*)(As + srow*40 + skc*8)      = a0;
    *(uint4*)(As + (64+srow)*40 + skc*8) = a1;
    *(uint4*)(Bs + srow*40 + skc*8)      = b0;
    *(uint4*)(Bs + (64+srow)*40 + skc*8) = b1;
    __syncthreads();
    bf16x8 af[4], bfr[4];
    #pragma unroll
    for (int i=0;i<4;i++) af[i]  = *(const bf16x8*)(As + (wm*64 + i*16 + fr)*40 + kq);
    #pragma unroll
    for (int j=0;j<4;j++) bfr[j] = *(const bf16x8*)(Bs + (wn*64 + j*16 + fr)*40 + kq);
    #pragma unroll
    for (int i=0;i<4;i++)
      #pragma unroll
      for (int j=0;j<4;j++)
        acc[i][j] = __builtin_amdgcn_mfma_f32_16x16x32_bf16(af[i], bfr[j], acc[i][j], 0,0,0);
  }
  const int crow = (lane >> 4) * 4, cn = lane & 15;
  #pragma unroll
  for (int i=0;i<4;i++)
    #pragma unroll
    for (int j=0;j<4;j++){
      long base = (long)(m0 + wm*64 + i*16 + crow)*ldc + (n0 + wn*64 + j*16 + cn);
      #pragma unroll
      for (int r=0;r<4;r++)
        C[base + (long)r*ldc] = acc[i][j][r];
    }
}

// ---- depthwise conv4 + bias + SiLU (f32 in/out); seed yb = Dp * x ----
__global__ __launch_bounds__(256) void conv_act_f32(const float* __restrict__ zx,
    const float* __restrict__ cw, const float* __restrict__ cb, const float* __restrict__ Dp,
    float* __restrict__ xconv, float* __restrict__ yb, int l0){
  int c = blockIdx.x*256 + threadIdx.x;             // 0..2303
  int by = blockIdx.y;                              // 0..CL-1
  int l = l0 + by;                                  // within-batch position
  float acc = cb[c];
  #pragma unroll
  for (int j=0;j<4;j++){
    if (l - 3 + j >= 0)
      acc = fmaf(zx[(size_t)(by+j)*NPAD + DINNER + c], cw[c*4+j], acc);
  }
  float v = acc / (1.f + expf(-acc));
  xconv[(size_t)by*CONVDIM + c] = v;
  if (c < DINNER) yb[(size_t)by*DINNER + c] = Dp[c>>6] * v;
}

// ---- dt = softplus(dt_raw + bias); dA = exp(dt * -exp(A_log)) ----
__global__ __launch_bounds__(256) void dt_f32(const float* __restrict__ zx,
    const float* __restrict__ dtb, const float* __restrict__ alog,
    float* __restrict__ dtv, float* __restrict__ dAv){
  int i = blockIdx.x*256 + threadIdx.x;             // < CL*32
  int lr = i >> 5, h = i & 31;
  float xv = zx[(size_t)(lr+3)*NPAD + (DINNER + CONVDIM) + h] + dtb[h];
  float sp = (xv > 20.f) ? xv : log1pf(expf(xv));
  float A = -expf(alog[h]);
  dtv[i] = sp;
  dAv[i] = expf(sp * A);
}

// ---- selective scan: grid (16 n-slices, 32 heads); 2 states/thread; state persists ----
__global__ __launch_bounds__(256) void scan_f32(const float* __restrict__ xconv,
    const float* __restrict__ dtv, const float* __restrict__ dAv,
    float* __restrict__ yb, float2* __restrict__ hstate, int b, int init){
  const int nb = blockIdx.x, h = blockIdx.y;
  const int tid = threadIdx.x;
  const int p = tid >> 2, q = tid & 3;
  __shared__ float xs[64*64];
  __shared__ float Bsm[64*8];
  __shared__ float Csm[64*8];
  __shared__ float dts[64], dAs[64];
  const int hidx = ((b*NHEADS + h)*16 + nb)*256 + tid;
  float h0=0.f,h1=0.f;
  if (!init){ float2 hs = hstate[hidx]; h0=hs.x; h1=hs.y; }
  for (int c0 = 0; c0 < CL; c0 += 64){
    __syncthreads();
    #pragma unroll
    for (int i=0;i<4;i++){
      int v = tid + i*256;
      int r = v >> 4, c4 = v & 15;
      *(float4*)&xs[r*64 + c4*4] =
        *(const float4*)(xconv + (size_t)(c0 + r)*CONVDIM + h*64 + c4*4);
    }
    if (tid < 128){
      int r = tid >> 1, c4 = tid & 1;
      *(float4*)&Bsm[r*8 + c4*4] =
        *(const float4*)(xconv + (size_t)(c0 + r)*CONVDIM + DINNER + nb*8 + c4*4);
    } else {
      int t2 = tid - 128, r = t2 >> 1, c4 = t2 & 1;
      *(float4*)&Csm[r*8 + c4*4] =
        *(const float4*)(xconv + (size_t)(c0 + r)*CONVDIM + DINNER + DSTATE + nb*8 + c4*4);
    }
    if (tid < 64) dts[tid] = dtv[(size_t)(c0 + tid)*NHEADS + h];
    else if (tid < 128) dAs[tid-64] = dAv[(size_t)(c0 + tid - 64)*NHEADS + h];
    __syncthreads();
    #pragma unroll 4
    for (int s=0;s<64;s++){
      float xv = xs[s*64 + p];
      float a  = dts[s] * xv;
      float dA = dAs[s];
      float2 Bv = *(float2*)&Bsm[s*8 + q*2];
      float2 Cv = *(float2*)&Csm[s*8 + q*2];
      h0 = fmaf(h0, dA, Bv.x*a);
      h1 = fmaf(h1, dA, Bv.y*a);
      float y = fmaf(h0, Cv.x, h1*Cv.y);
      y += __shfl_xor(y, 1);
      y += __shfl_xor(y, 2);
      if (q == 0) atomicAdd(&yb[(size_t)(c0 + s)*DINNER + h*64 + p], y);
    }
  }
  float2 hs; hs.x=h0; hs.y=h1;
  hstate[hidx] = hs;
}

// ---- y *= silu(z); RMSNorm(2048) * norm_w -> yg (bf16) ----
__global__ __launch_bounds__(256) void gate_norm_f32(const float* __restrict__ yb,
    const float* __restrict__ zx, const float* __restrict__ nw,
    ushort* __restrict__ yg){
  int lr = blockIdx.x, tid = threadIdx.x;
  int d0 = tid*8;
  const float* yrow = yb + (size_t)lr*DINNER;
  const float* zrow = zx + (size_t)(lr+3)*NPAD;
  float y[8]; float ss = 0.f;
  #pragma unroll
  for (int i=0;i<8;i++){
    float z = zrow[d0+i];
    float g = z / (1.f + expf(-z));
    float v = yrow[d0+i] * g;
    y[i] = v; ss += v*v;
  }
  #pragma unroll
  for (int m=1;m<64;m<<=1) ss += __shfl_xor(ss, m);
  __shared__ float red[4];
  if ((tid & 63) == 0) red[tid>>6] = ss;
  __syncthreads();
  ss = red[0]+red[1]+red[2]+red[3];
  float scale = rsqrtf(ss * (1.f/DINNER) + 1e-5f);
  ushort* out = yg + (size_t)lr*DINNER;
  #pragma unroll
  for (int i=0;i<8;i++)
    out[d0+i] = f2bf(y[i] * scale * nw[d0+i]);
}

extern "C" void kernel_launch(void* const* d_in, const int* in_sizes, int n_in,
                              void* d_out, int out_size, void* d_ws, size_t ws_size,
                              hipStream_t stream) {
  const float* x    = (const float*)d_in[0];
  const float* ipw  = (const float*)d_in[1];
  const float* cw   = (const float*)d_in[2];
  const float* cb   = (const float*)d_in[3];
  const float* dtb  = (const float*)d_in[4];
  const float* alog = (const float*)d_in[5];
  const float* Dp   = (const float*)d_in[6];
  const float* nw   = (const float*)d_in[7];
  const float* opw  = (const float*)d_in[8];
  char* ws = (char*)d_ws;
  size_t off = 0;
  ushort* xbf    = (ushort*)(ws + off); off += (size_t)ROWS*DMODEL*2;      // 16.8 MB
  ushort* Wp     = (ushort*)(ws + off); off += (size_t)NPAD*DMODEL*2;      //  9.2 MB
  ushort* opwb   = (ushort*)(ws + off); off += (size_t)DMODEL*DINNER*2;    //  4.2 MB
  float*  zxb    = (float*)(ws + off);  off += (size_t)CR*NPAD*4;          // 20.6 MB
  float*  xconv  = (float*)(ws + off);  off += (size_t)CL*CONVDIM*4;       //  9.4 MB
  float*  dtv    = (float*)(ws + off);  off += (size_t)CL*NHEADS*4;        //  0.13 MB
  float*  dAv    = (float*)(ws + off);  off += (size_t)CL*NHEADS*4;        //  0.13 MB
  float*  yb     = (float*)(ws + off);  off += (size_t)CL*DINNER*4;        //  8.4 MB
  ushort* yg     = (ushort*)(ws + off); off += (size_t)CL*DINNER*2;        //  4.2 MB
  float2* hstate = (float2*)(ws + off); off += (size_t)2*NHEADS*16*256*8;  //  2.1 MB
  // total ~75 MB

  cvt_k<<<ROWS*DMODEL/8/256, 256, 0, stream>>>((const float4*)x, (uint4*)xbf);
  padw_cvt<<<NPAD, 256, 0, stream>>>((const float4*)ipw, (ushort4*)Wp);
  cvt_k<<<DMODEL*DINNER/8/256, 256, 0, stream>>>((const float4*)opw, (uint4*)opwb);

  for (int ck = 0; ck < 8; ck++){
    int b  = ck >> 2;
    int l0 = (ck & 3) * CL;
    long grow0 = (long)b*LL + l0 - 3;
    gemm_bt<<<dim3(NPAD/128, CR/128), 256, 0, stream>>>(
        xbf, DMODEL, grow0, (long)ROWS-1, Wp, zxb, NPAD, DMODEL);
    conv_act_f32<<<dim3(CONVDIM/256, CL), 256, 0, stream>>>(
        zxb, cw, cb, Dp, xconv, yb, l0);
    dt_f32<<<CL*NHEADS/256, 256, 0, stream>>>(zxb, dtb, alog, dtv, dAv);
    scan_f32<<<dim3(16, NHEADS), 256, 0, stream>>>(
        xconv, dtv, dAv, yb, hstate, b, (l0==0)?1:0);
    gate_norm_f32<<<CL, 256, 0, stream>>>(yb, zxb, nw, yg);
    gemm_bt<<<dim3(DMODEL/128, CL/128), 256, 0, stream>>>(
        yg, DINNER, 0, (long)CL-1, opwb,
        (float*)d_out + (size_t)(b*LL + l0)*DMODEL, DMODEL, DINNER);
  }
}

// Round 7
// 1915.297 us; speedup vs baseline: 1.8953x; 1.1449x over previous
//
#include <hip/hip_runtime.h>

#define LL 4096
#define DMODEL 1024
#define DINNER 2048
#define NHEADS 32
#define DSTATE 128
#define DINPROJ 4384
#define NPAD 4480          // 35*128 padded gemm1 N; zxb f32 row stride
#define CONVDIM 2304
#define ROWS 8192
#define CL 1024            // rows per L-chunk
#define CR 1152            // 9*128 rows computed by gemm1 per chunk (CL + 3 halo)
#define Q 64               // scan sub-chunk
#define NC 16              // sub-chunks per scan launch (CL/Q)

typedef __attribute__((ext_vector_type(8))) __bf16 bf16x8;
typedef __attribute__((ext_vector_type(4))) float f32x4;

__device__ __forceinline__ float bf2f(ushort u){ union{uint i;float f;} v; v.i=(uint)u<<16; return v.f; }
__device__ __forceinline__ ushort f2bf(float f){ union{float f;uint i;} v; v.f=f; uint r=v.i+0x7fffu+((v.i>>16)&1u); return (ushort)(r>>16); }

// ---- f32 -> bf16, 8 elems/thread ----
__global__ __launch_bounds__(256) void cvt_k(const float4* __restrict__ src, uint4* __restrict__ dst){
  long t = (long)blockIdx.x*256 + threadIdx.x;
  float4 a = src[t*2], b = src[t*2+1];
  ushort u[8] = { f2bf(a.x),f2bf(a.y),f2bf(a.z),f2bf(a.w),
                  f2bf(b.x),f2bf(b.y),f2bf(b.z),f2bf(b.w) };
  dst[t] = *(uint4*)u;
}

// ---- in_proj_w f32 (4384x1024) -> padded bf16 (4480x1024) ----
__global__ __launch_bounds__(256) void padw_cvt(const float4* __restrict__ W, ushort4* __restrict__ Wp){
  int row = blockIdx.x, c = threadIdx.x;
  ushort4 o = make_ushort4(0,0,0,0);
  if (row < DINPROJ){
    float4 f = W[(size_t)row*256 + c];
    o = make_ushort4(f2bf(f.x), f2bf(f.y), f2bf(f.z), f2bf(f.w));
  }
  Wp[(size_t)row*256 + c] = o;
}

// ---- bf16 MFMA GEMM: C_f32[m,n] = A[clamp(grow0+m)][:K] . W[n][:K] ----
__global__ __launch_bounds__(256) void gemm_bt(
    const ushort* __restrict__ A, int lda, long grow0, long rowmax,
    const ushort* __restrict__ W,
    float* __restrict__ C, int ldc, int K){
  __shared__ ushort As[128*40];
  __shared__ ushort Bs[128*40];
  const int tid = threadIdx.x;
  const int lane = tid & 63, wave = tid >> 6;
  const int wm = wave >> 1, wn = wave & 1;
  const int m0 = blockIdx.y * 128, n0 = blockIdx.x * 128;
  const int srow = tid >> 2, skc = tid & 3;
  const int fr = lane & 15, kq = (lane >> 4) * 8;
  long ga0 = grow0 + m0 + srow;      if (ga0 < 0) ga0 = 0; if (ga0 > rowmax) ga0 = rowmax;
  long ga1 = grow0 + m0 + 64 + srow; if (ga1 < 0) ga1 = 0; if (ga1 > rowmax) ga1 = rowmax;
  f32x4 acc[4][4] = {};
  for (int k0 = 0; k0 < K; k0 += 32){
    uint4 a0 = *(const uint4*)(A + ga0*(long)lda + k0 + skc*8);
    uint4 a1 = *(const uint4*)(A + ga1*(long)lda + k0 + skc*8);
    uint4 b0 = *(const uint4*)(W + (size_t)(n0 + srow)*K      + k0 + skc*8);
    uint4 b1 = *(const uint4*)(W + (size_t)(n0 + 64 + srow)*K + k0 + skc*8);
    __syncthreads();
    *(uint4*)(As + srow*40 + skc*8)      = a0;
    *(uint4*)(As + (64+srow)*40 + skc*8) = a1;
    *(uint4*)(Bs + srow*40 + skc*8)      = b0;
    *(uint4*)(Bs + (64+srow)*40 + skc*8) = b1;
    __syncthreads();
    bf16x8 af[4], bfr[4];
    #pragma unroll
    for (int i=0;i<4;i++) af[i]  = *(const bf16x8*)(As + (wm*64 + i*16 + fr)*40 + kq);
    #pragma unroll
    for (int j=0;j<4;j++) bfr[j] = *(const bf16x8*)(Bs + (wn*64 + j*16 + fr)*40 + kq);
    #pragma unroll
    for (int i=0;i<4;i++)
      #pragma unroll
      for (int j=0;j<4;j++)
        acc[i][j] = __builtin_amdgcn_mfma_f32_16x16x32_bf16(af[i], bfr[j], acc[i][j], 0,0,0);
  }
  const int crow = (lane >> 4) * 4, cn = lane & 15;
  #pragma unroll
  for (int i=0;i<4;i++)
    #pragma unroll
    for (int j=0;j<4;j++){
      long base = (long)(m0 + wm*64 + i*16 + crow)*ldc + (n0 + wn*64 + j*16 + cn);
      #pragma unroll
      for (int r=0;r<4;r++)
        C[base + (long)r*ldc] = acc[i][j][r];
    }
}

// ---- depthwise conv4 + bias + SiLU; bf16 out ----
__global__ __launch_bounds__(256) void conv_act(const float* __restrict__ zx,
    const float* __restrict__ cw, const float* __restrict__ cb,
    ushort* __restrict__ xconv, int l0){
  int c = blockIdx.x*256 + threadIdx.x;             // 0..2303
  int by = blockIdx.y;                              // 0..CL-1
  int l = l0 + by;
  float acc = cb[c];
  #pragma unroll
  for (int j=0;j<4;j++){
    if (l - 3 + j >= 0)
      acc = fmaf(zx[(size_t)(by+j)*NPAD + DINNER + c], cw[c*4+j], acc);
  }
  float v = acc / (1.f + expf(-acc));
  xconv[(size_t)by*CONVDIM + c] = f2bf(v);
}

// ---- dt = softplus(dt_raw + bias); la = dt * A (log decay, NOT exp'd) ----
__global__ __launch_bounds__(256) void dt_f32(const float* __restrict__ zx,
    const float* __restrict__ dtb, const float* __restrict__ alog,
    float* __restrict__ dtv, float* __restrict__ lav){
  int i = blockIdx.x*256 + threadIdx.x;             // < CL*32
  int lr = i >> 5, h = i & 31;
  float xv = zx[(size_t)(lr+3)*NPAD + (DINNER + CONVDIM) + h] + dtb[h];
  float sp = (xv > 20.f) ? xv : log1pf(expf(xv));
  float A = -expf(alog[h]);
  dtv[i] = sp;
  lav[i] = sp * A;
}

// ---- chunked matmul scan: grid = 32 heads; 256 thr = 4 waves; h carried in regs ----
// per sub-chunk (Q=64): S=C.B^T; P=S*L*dt; y = e^lg*(C.h) + P.X + Dp*x; h = e^lg63*h + X^T.Bw
__global__ __launch_bounds__(256) void scan_mm(const ushort* __restrict__ xcv,
    const float* __restrict__ dtv, const float* __restrict__ lav,
    const float* __restrict__ Dp, ushort* __restrict__ yb,
    f32x4* __restrict__ hstate, int b, int init){
  const int h = blockIdx.x;
  const int tid = threadIdx.x, lane = tid & 63, w = tid >> 6;
  const int l15 = lane & 15, quad = lane >> 4, kq = quad*8;
  __shared__ float lg[Q], dts[Q], wsx[Q], els[Q];
  __shared__ __align__(16) ushort XT[64*72];    // [p][s]
  __shared__ __align__(16) ushort BTw[128*72];  // [n][s], weighted
  __shared__ __align__(16) ushort Ps[64*72];    // [t][s]
  __shared__ __align__(16) ushort hbT[64*136];  // [p][n] bf16 copy of h
  f32x4 hacc[8];   // h[p = quad*4+r][n = 16j + l15], p-tile w
  const long hbase = (((long)b*NHEADS + h)*4 + w)*512;
  if (init){
    #pragma unroll
    for (int j=0;j<8;j++) hacc[j] = (f32x4){0.f,0.f,0.f,0.f};
  } else {
    #pragma unroll
    for (int j=0;j<8;j++) hacc[j] = hstate[hbase + lane*8 + j];
  }
  const float dph = Dp[h];
  for (int sc = 0; sc < NC; sc++){
    const int c0 = sc*Q;
    // A0: log-decay prefix scan (wave 0)
    if (tid < 64){
      float la = lav[(size_t)(c0+tid)*NHEADS + h];
      float dt = dtv[(size_t)(c0+tid)*NHEADS + h];
      float v = la;
      #pragma unroll
      for (int off=1; off<64; off<<=1){ float u = __shfl_up(v, off); if (tid >= off) v += u; }
      float tot = __shfl(v, 63);
      lg[tid]=v; dts[tid]=dt; wsx[tid]=__expf(tot - v)*dt; els[tid]=__expf(v);
    }
    // A1: stage hbT (bf16 h copy) from regs; each wave its own p-tile rows
    #pragma unroll
    for (int j=0;j<8;j++)
      #pragma unroll
      for (int r=0;r<4;r++)
        hbT[(16*w + quad*4 + r)*136 + 16*j + l15] = f2bf(hacc[j][r]);
    __syncthreads();
    // A2: stage XT (x transposed) and BTw (weighted B transposed)
    { int s = tid>>2, pb = (tid&3)*16;
      const ushort* src = xcv + (size_t)(c0+s)*CONVDIM + h*64 + pb;
      ushort tmp[16];
      *(uint4*)tmp     = *(const uint4*)src;
      *(uint4*)(tmp+8) = *(const uint4*)(src+8);
      #pragma unroll
      for (int i=0;i<16;i++) XT[(pb+i)*72 + s] = tmp[i];
    }
    { int s = tid>>2, nb4 = (tid&3)*32;
      const ushort* src = xcv + (size_t)(c0+s)*CONVDIM + DINNER + nb4;
      float wv = wsx[s];
      ushort tmp[32];
      #pragma unroll
      for (int v4=0;v4<4;v4++) *(uint4*)(tmp+v4*8) = *(const uint4*)(src+v4*8);
      #pragma unroll
      for (int i=0;i<32;i++) BTw[(nb4+i)*72 + s] = f2bf(bf2f(tmp[i])*wv);
    }
    __syncthreads();
    // B: S = C.B^T (wave w -> t-rows 16w), then P = S * L * dt -> Ps
    {
      const ushort* Crow = xcv + (size_t)(c0 + 16*w + l15)*CONVDIM + DINNER + DSTATE;
      f32x4 sac[4] = {};
      #pragma unroll
      for (int kb=0;kb<4;kb++){
        bf16x8 afr = *(const bf16x8*)(Crow + kb*32 + kq);
        #pragma unroll
        for (int j=0;j<4;j++){
          const ushort* Brow = xcv + (size_t)(c0 + 16*j + l15)*CONVDIM + DINNER;
          bf16x8 bfr = *(const bf16x8*)(Brow + kb*32 + kq);
          sac[j] = __builtin_amdgcn_mfma_f32_16x16x32_bf16(afr, bfr, sac[j], 0,0,0);
        }
      }
      #pragma unroll
      for (int j=0;j<4;j++){
        int s = 16*j + l15;
        float lgs = lg[s], dtss = dts[s];
        #pragma unroll
        for (int r=0;r<4;r++){
          int t = 16*w + quad*4 + r;
          float val = (t >= s) ? sac[j][r]*__expf(lg[t]-lgs)*dtss : 0.f;
          Ps[t*72 + s] = f2bf(val);
        }
      }
    }
    __syncthreads();
    // C: y tiles (wave w -> p-tile w); y = els[t]*(C.h) + P.X + Dp*x
    {
      bf16x8 hb[4], xb[2];
      #pragma unroll
      for (int kb=0;kb<4;kb++) hb[kb] = *(const bf16x8*)(hbT + (16*w + l15)*136 + kb*32 + kq);
      #pragma unroll
      for (int kb=0;kb<2;kb++) xb[kb] = *(const bf16x8*)(XT  + (16*w + l15)*72  + kb*32 + kq);
      #pragma unroll
      for (int i=0;i<4;i++){
        const ushort* Crow = xcv + (size_t)(c0 + 16*i + l15)*CONVDIM + DINNER + DSTATE;
        f32x4 y2 = {};   // C.h (unscaled)
        #pragma unroll
        for (int kb=0;kb<4;kb++){
          bf16x8 afr = *(const bf16x8*)(Crow + kb*32 + kq);
          y2 = __builtin_amdgcn_mfma_f32_16x16x32_bf16(afr, hb[kb], y2, 0,0,0);
        }
        f32x4 y1 = {};   // P.X
        #pragma unroll
        for (int kb=0;kb<2;kb++){
          bf16x8 afr = *(const bf16x8*)(Ps + (16*i + l15)*72 + kb*32 + kq);
          y1 = __builtin_amdgcn_mfma_f32_16x16x32_bf16(afr, xb[kb], y1, 0,0,0);
        }
        int p = 16*w + l15;
        #pragma unroll
        for (int r=0;r<4;r++){
          int t = 16*i + quad*4 + r;
          float xv = bf2f(XT[p*72 + t]);
          float yv = y1[r] + els[t]*y2[r] + dph*xv;
          yb[(size_t)(c0 + t)*DINNER + h*64 + p] = f2bf(yv);
        }
      }
    }
    // D: h update: h = els[63]*h + X^T.Bw
    {
      float sc63 = els[63];
      #pragma unroll
      for (int j=0;j<8;j++){
        hacc[j][0]*=sc63; hacc[j][1]*=sc63; hacc[j][2]*=sc63; hacc[j][3]*=sc63;
      }
      #pragma unroll
      for (int kb=0;kb<2;kb++){
        bf16x8 afr = *(const bf16x8*)(XT + (16*w + l15)*72 + kb*32 + kq);
        #pragma unroll
        for (int j=0;j<8;j++){
          bf16x8 bfr = *(const bf16x8*)(BTw + (16*j + l15)*72 + kb*32 + kq);
          hacc[j] = __builtin_amdgcn_mfma_f32_16x16x32_bf16(afr, bfr, hacc[j], 0,0,0);
        }
      }
    }
    __syncthreads();
  }
  #pragma unroll
  for (int j=0;j<8;j++) hstate[hbase + lane*8 + j] = hacc[j];
}

// ---- y(bf16) *= silu(z); RMSNorm(2048) * norm_w -> yg (bf16) ----
__global__ __launch_bounds__(256) void gate_norm_f32(const ushort* __restrict__ yb,
    const float* __restrict__ zx, const float* __restrict__ nw,
    ushort* __restrict__ yg){
  int lr = blockIdx.x, tid = threadIdx.x;
  int d0 = tid*8;
  const ushort* yrow = yb + (size_t)lr*DINNER;
  const float* zrow = zx + (size_t)(lr+3)*NPAD;
  float y[8]; float ss = 0.f;
  #pragma unroll
  for (int i=0;i<8;i++){
    float z = zrow[d0+i];
    float g = z / (1.f + expf(-z));
    float v = bf2f(yrow[d0+i]) * g;
    y[i] = v; ss += v*v;
  }
  #pragma unroll
  for (int m=1;m<64;m<<=1) ss += __shfl_xor(ss, m);
  __shared__ float red[4];
  if ((tid & 63) == 0) red[tid>>6] = ss;
  __syncthreads();
  ss = red[0]+red[1]+red[2]+red[3];
  float scale = rsqrtf(ss * (1.f/DINNER) + 1e-5f);
  ushort* out = yg + (size_t)lr*DINNER;
  #pragma unroll
  for (int i=0;i<8;i++)
    out[d0+i] = f2bf(y[i] * scale * nw[d0+i]);
}

extern "C" void kernel_launch(void* const* d_in, const int* in_sizes, int n_in,
                              void* d_out, int out_size, void* d_ws, size_t ws_size,
                              hipStream_t stream) {
  const float* x    = (const float*)d_in[0];
  const float* ipw  = (const float*)d_in[1];
  const float* cw   = (const float*)d_in[2];
  const float* cb   = (const float*)d_in[3];
  const float* dtb  = (const float*)d_in[4];
  const float* alog = (const float*)d_in[5];
  const float* Dp   = (const float*)d_in[6];
  const float* nw   = (const float*)d_in[7];
  const float* opw  = (const float*)d_in[8];
  char* ws = (char*)d_ws;
  size_t off = 0;
  ushort* xbf    = (ushort*)(ws + off); off += (size_t)ROWS*DMODEL*2;      // 16.8 MB
  ushort* Wp     = (ushort*)(ws + off); off += (size_t)NPAD*DMODEL*2;      //  9.2 MB
  ushort* opwb   = (ushort*)(ws + off); off += (size_t)DMODEL*DINNER*2;    //  4.2 MB
  float*  zxb    = (float*)(ws + off);  off += (size_t)CR*NPAD*4;          // 20.6 MB
  ushort* xconv  = (ushort*)(ws + off); off += (size_t)CL*CONVDIM*2;       //  4.7 MB
  float*  dtv    = (float*)(ws + off);  off += (size_t)CL*NHEADS*4;        //  0.13 MB
  float*  lav    = (float*)(ws + off);  off += (size_t)CL*NHEADS*4;        //  0.13 MB
  ushort* yb     = (ushort*)(ws + off); off += (size_t)CL*DINNER*2;        //  4.2 MB
  ushort* yg     = (ushort*)(ws + off); off += (size_t)CL*DINNER*2;        //  4.2 MB
  f32x4*  hstate = (f32x4*)(ws + off);  off += (size_t)2*NHEADS*4*512*16;  //  4.2 MB
  // total ~68 MB

  cvt_k<<<ROWS*DMODEL/8/256, 256, 0, stream>>>((const float4*)x, (uint4*)xbf);
  padw_cvt<<<NPAD, 256, 0, stream>>>((const float4*)ipw, (ushort4*)Wp);
  cvt_k<<<DMODEL*DINNER/8/256, 256, 0, stream>>>((const float4*)opw, (uint4*)opwb);

  for (int ck = 0; ck < 8; ck++){
    int b  = ck >> 2;
    int l0 = (ck & 3) * CL;
    long grow0 = (long)b*LL + l0 - 3;
    gemm_bt<<<dim3(NPAD/128, CR/128), 256, 0, stream>>>(
        xbf, DMODEL, grow0, (long)ROWS-1, Wp, zxb, NPAD, DMODEL);
    conv_act<<<dim3(CONVDIM/256, CL), 256, 0, stream>>>(zxb, cw, cb, xconv, l0);
    dt_f32<<<CL*NHEADS/256, 256, 0, stream>>>(zxb, dtb, alog, dtv, lav);
    scan_mm<<<NHEADS, 256, 0, stream>>>(xconv, dtv, lav, Dp, yb, hstate, b, (l0==0)?1:0);
    gate_norm_f32<<<CL, 256, 0, stream>>>(yb, zxb, nw, yg);
    gemm_bt<<<dim3(DMODEL/128, CL/128), 256, 0, stream>>>(
        yg, DINNER, 0, (long)CL-1, opwb,
        (float*)d_out + (size_t)(b*LL + l0)*DMODEL, DMODEL, DINNER);
  }
}

// Round 8
// 1261.540 us; speedup vs baseline: 2.8774x; 1.5182x over previous
//
#include <hip/hip_runtime.h>

#define LL 4096
#define DMODEL 1024
#define DINNER 2048
#define NHEADS 32
#define DSTATE 128
#define DINPROJ 4384
#define NPAD 4480          // 35*128 padded gemm1 N; zxb f32 row stride
#define CONVDIM 2304
#define ROWS 8192
#define CL 1024            // rows per L-chunk
#define CR 1152            // 9*128 rows computed by gemm1 per chunk (CL + 3 halo)
#define Q 64               // scan sub-chunk
#define NC 16              // sub-chunks per scan launch (CL/Q)

typedef __attribute__((ext_vector_type(8))) __bf16 bf16x8;
typedef __attribute__((ext_vector_type(4))) float f32x4;

__device__ __forceinline__ float bf2f(ushort u){ union{uint i;float f;} v; v.i=(uint)u<<16; return v.f; }
__device__ __forceinline__ ushort f2bf(float f){ union{float f;uint i;} v; v.f=f; uint r=v.i+0x7fffu+((v.i>>16)&1u); return (ushort)(r>>16); }

// ---- f32 -> bf16, 8 elems/thread ----
__global__ __launch_bounds__(256) void cvt_k(const float4* __restrict__ src, uint4* __restrict__ dst){
  long t = (long)blockIdx.x*256 + threadIdx.x;
  float4 a = src[t*2], b = src[t*2+1];
  ushort u[8] = { f2bf(a.x),f2bf(a.y),f2bf(a.z),f2bf(a.w),
                  f2bf(b.x),f2bf(b.y),f2bf(b.z),f2bf(b.w) };
  dst[t] = *(uint4*)u;
}

// ---- in_proj_w f32 (4384x1024) -> padded bf16 (4480x1024) ----
__global__ __launch_bounds__(256) void padw_cvt(const float4* __restrict__ W, ushort4* __restrict__ Wp){
  int row = blockIdx.x, c = threadIdx.x;
  ushort4 o = make_ushort4(0,0,0,0);
  if (row < DINPROJ){
    float4 f = W[(size_t)row*256 + c];
    o = make_ushort4(f2bf(f.x), f2bf(f.y), f2bf(f.z), f2bf(f.w));
  }
  Wp[(size_t)row*256 + c] = o;
}

// ---- bf16 MFMA GEMM: C_f32[m,n] = A[clamp(grow0+m)][:K] . W[n][:K] ----
__global__ __launch_bounds__(256) void gemm_bt(
    const ushort* __restrict__ A, int lda, long grow0, long rowmax,
    const ushort* __restrict__ W,
    float* __restrict__ C, int ldc, int K){
  __shared__ ushort As[128*40];
  __shared__ ushort Bs[128*40];
  const int tid = threadIdx.x;
  const int lane = tid & 63, wave = tid >> 6;
  const int wm = wave >> 1, wn = wave & 1;
  const int m0 = blockIdx.y * 128, n0 = blockIdx.x * 128;
  const int srow = tid >> 2, skc = tid & 3;
  const int fr = lane & 15, kq = (lane >> 4) * 8;
  long ga0 = grow0 + m0 + srow;      if (ga0 < 0) ga0 = 0; if (ga0 > rowmax) ga0 = rowmax;
  long ga1 = grow0 + m0 + 64 + srow; if (ga1 < 0) ga1 = 0; if (ga1 > rowmax) ga1 = rowmax;
  f32x4 acc[4][4] = {};
  for (int k0 = 0; k0 < K; k0 += 32){
    uint4 a0 = *(const uint4*)(A + ga0*(long)lda + k0 + skc*8);
    uint4 a1 = *(const uint4*)(A + ga1*(long)lda + k0 + skc*8);
    uint4 b0 = *(const uint4*)(W + (size_t)(n0 + srow)*K      + k0 + skc*8);
    uint4 b1 = *(const uint4*)(W + (size_t)(n0 + 64 + srow)*K + k0 + skc*8);
    __syncthreads();
    *(uint4*)(As + srow*40 + skc*8)      = a0;
    *(uint4*)(As + (64+srow)*40 + skc*8) = a1;
    *(uint4*)(Bs + srow*40 + skc*8)      = b0;
    *(uint4*)(Bs + (64+srow)*40 + skc*8) = b1;
    __syncthreads();
    bf16x8 af[4], bfr[4];
    #pragma unroll
    for (int i=0;i<4;i++) af[i]  = *(const bf16x8*)(As + (wm*64 + i*16 + fr)*40 + kq);
    #pragma unroll
    for (int j=0;j<4;j++) bfr[j] = *(const bf16x8*)(Bs + (wn*64 + j*16 + fr)*40 + kq);
    #pragma unroll
    for (int i=0;i<4;i++)
      #pragma unroll
      for (int j=0;j<4;j++)
        acc[i][j] = __builtin_amdgcn_mfma_f32_16x16x32_bf16(af[i], bfr[j], acc[i][j], 0,0,0);
  }
  const int crow = (lane >> 4) * 4, cn = lane & 15;
  #pragma unroll
  for (int i=0;i<4;i++)
    #pragma unroll
    for (int j=0;j<4;j++){
      long base = (long)(m0 + wm*64 + i*16 + crow)*ldc + (n0 + wn*64 + j*16 + cn);
      #pragma unroll
      for (int r=0;r<4;r++)
        C[base + (long)r*ldc] = acc[i][j][r];
    }
}

// ---- depthwise conv4 + bias + SiLU; bf16 out ----
__global__ __launch_bounds__(256) void conv_act(const float* __restrict__ zx,
    const float* __restrict__ cw, const float* __restrict__ cb,
    ushort* __restrict__ xconv, int l0){
  int c = blockIdx.x*256 + threadIdx.x;             // 0..2303
  int by = blockIdx.y;                              // 0..CL-1
  int l = l0 + by;
  float acc = cb[c];
  #pragma unroll
  for (int j=0;j<4;j++){
    if (l - 3 + j >= 0)
      acc = fmaf(zx[(size_t)(by+j)*NPAD + DINNER + c], cw[c*4+j], acc);
  }
  float v = acc / (1.f + expf(-acc));
  xconv[(size_t)by*CONVDIM + c] = f2bf(v);
}

// ---- dt = softplus(dt_raw + bias); la = dt * A (log decay) ----
__global__ __launch_bounds__(256) void dt_f32(const float* __restrict__ zx,
    const float* __restrict__ dtb, const float* __restrict__ alog,
    float* __restrict__ dtv, float* __restrict__ lav){
  int i = blockIdx.x*256 + threadIdx.x;             // < CL*32
  int lr = i >> 5, h = i & 31;
  float xv = zx[(size_t)(lr+3)*NPAD + (DINNER + CONVDIM) + h] + dtb[h];
  float sp = (xv > 20.f) ? xv : log1pf(expf(xv));
  float A = -expf(alog[h]);
  dtv[i] = sp;
  lav[i] = sp * A;
}

// ---- scan phase 1: per (chunk,head) decay prefix + G = X^T.Bw; grid (NC, NHEADS) ----
__global__ __launch_bounds__(256) void scan_pre(const ushort* __restrict__ xcv,
    const float* __restrict__ dtv, const float* __restrict__ lav,
    ushort* __restrict__ gbuf, float* __restrict__ lgbuf){
  const int c = blockIdx.x, h = blockIdx.y;
  const int tid = threadIdx.x, lane = tid & 63, w = tid >> 6;
  const int l15 = lane & 15, quad = lane >> 4, kq = quad*8;
  __shared__ float wsx[Q];
  __shared__ __align__(16) ushort XT[64*72];    // [p][s]
  __shared__ __align__(16) ushort BTw[128*72];  // [n][s], weighted
  const int c0 = c*Q;
  if (tid < 64){
    float la = lav[(size_t)(c0+tid)*NHEADS + h];
    float dt = dtv[(size_t)(c0+tid)*NHEADS + h];
    float v = la;
    #pragma unroll
    for (int off=1; off<64; off<<=1){ float u = __shfl_up(v, off); if (tid >= off) v += u; }
    float tot = __shfl(v, 63);
    wsx[tid] = __expf(tot - v)*dt;
    lgbuf[((size_t)h*NC + c)*Q + tid] = v;
  }
  __syncthreads();
  { int s = tid>>2, pb = (tid&3)*16;
    const ushort* src = xcv + (size_t)(c0+s)*CONVDIM + h*64 + pb;
    ushort tmp[16];
    *(uint4*)tmp     = *(const uint4*)src;
    *(uint4*)(tmp+8) = *(const uint4*)(src+8);
    #pragma unroll
    for (int i=0;i<16;i++) XT[(pb+i)*72 + s] = tmp[i];
  }
  { int s = tid>>2, nb4 = (tid&3)*32;
    const ushort* src = xcv + (size_t)(c0+s)*CONVDIM + DINNER + nb4;
    float wv = wsx[s];
    ushort tmp[32];
    #pragma unroll
    for (int v4=0;v4<4;v4++) *(uint4*)(tmp+v4*8) = *(const uint4*)(src+v4*8);
    #pragma unroll
    for (int i=0;i<32;i++) BTw[(nb4+i)*72 + s] = f2bf(bf2f(tmp[i])*wv);
  }
  __syncthreads();
  f32x4 g[8] = {};
  #pragma unroll
  for (int kb=0;kb<2;kb++){
    bf16x8 afr = *(const bf16x8*)(XT + (16*w + l15)*72 + kb*32 + kq);
    #pragma unroll
    for (int j=0;j<8;j++){
      bf16x8 bfr = *(const bf16x8*)(BTw + (16*j + l15)*72 + kb*32 + kq);
      g[j] = __builtin_amdgcn_mfma_f32_16x16x32_bf16(afr, bfr, g[j], 0,0,0);
    }
  }
  ushort* gdst = gbuf + ((size_t)h*NC + c)*8192;   // [p][n] row-major
  #pragma unroll
  for (int j=0;j<8;j++)
    #pragma unroll
    for (int r=0;r<4;r++)
      gdst[(16*w + quad*4 + r)*128 + 16*j + l15] = f2bf(g[j][r]);
}

// ---- scan phase 2: sequential carry over NC chunks; grid (NHEADS) ----
__global__ __launch_bounds__(256) void scan_carry(const ushort* __restrict__ gbuf,
    const float* __restrict__ lgbuf, ushort* __restrict__ hinit,
    float* __restrict__ hstate, int b, int init){
  const int h = blockIdx.x;
  const int tid = threadIdx.x;
  float hreg[32];
  float* hst = hstate + ((size_t)b*NHEADS + h)*8192 + (size_t)tid*32;
  if (init){
    #pragma unroll
    for (int i=0;i<32;i++) hreg[i] = 0.f;
  } else {
    #pragma unroll
    for (int k=0;k<8;k++){
      float4 v = *(const float4*)(hst + k*4);
      hreg[k*4]=v.x; hreg[k*4+1]=v.y; hreg[k*4+2]=v.z; hreg[k*4+3]=v.w;
    }
  }
  for (int c=0;c<NC;c++){
    const size_t base = ((size_t)h*NC + c)*8192 + (size_t)tid*32;
    ushort* hw = hinit + base;
    #pragma unroll
    for (int k=0;k<4;k++){
      ushort u[8];
      #pragma unroll
      for (int i=0;i<8;i++) u[i] = f2bf(hreg[k*8+i]);
      *(uint4*)(hw + k*8) = *(uint4*)u;
    }
    float e = __expf(lgbuf[((size_t)h*NC + c)*Q + 63]);
    const ushort* gr = gbuf + base;
    #pragma unroll
    for (int k=0;k<4;k++){
      uint4 gu = *(const uint4*)(gr + k*8);
      const ushort* gus = (const ushort*)&gu;
      #pragma unroll
      for (int i=0;i<8;i++) hreg[k*8+i] = fmaf(hreg[k*8+i], e, bf2f(gus[i]));
    }
  }
  #pragma unroll
  for (int k=0;k<8;k++)
    *(float4*)(hst + k*4) = make_float4(hreg[k*4],hreg[k*4+1],hreg[k*4+2],hreg[k*4+3]);
}

// ---- scan phase 3: y = els*(C.h_init) + P.X + Dp*x; grid (NC, NHEADS) ----
__global__ __launch_bounds__(256) void scan_y(const ushort* __restrict__ xcv,
    const float* __restrict__ dtv, const float* __restrict__ lgbuf,
    const ushort* __restrict__ hinit, const float* __restrict__ Dp,
    ushort* __restrict__ yb){
  const int c = blockIdx.x, h = blockIdx.y;
  const int tid = threadIdx.x, lane = tid & 63, w = tid >> 6;
  const int l15 = lane & 15, quad = lane >> 4, kq = quad*8;
  __shared__ float lg[Q], dts[Q], els[Q];
  __shared__ __align__(16) ushort XT[64*72];    // [p][s]
  __shared__ __align__(16) ushort Ps[64*72];    // [t][s]
  const int c0 = c*Q;
  if (tid < 64){
    float v = lgbuf[((size_t)h*NC + c)*Q + tid];
    lg[tid] = v;
    els[tid] = __expf(v);
    dts[tid] = dtv[(size_t)(c0+tid)*NHEADS + h];
  }
  { int s = tid>>2, pb = (tid&3)*16;
    const ushort* src = xcv + (size_t)(c0+s)*CONVDIM + h*64 + pb;
    ushort tmp[16];
    *(uint4*)tmp     = *(const uint4*)src;
    *(uint4*)(tmp+8) = *(const uint4*)(src+8);
    #pragma unroll
    for (int i=0;i<16;i++) XT[(pb+i)*72 + s] = tmp[i];
  }
  __syncthreads();
  // S = C.B^T (wave w -> t-rows 16w), P = S * L * dt -> Ps
  {
    const ushort* Crow = xcv + (size_t)(c0 + 16*w + l15)*CONVDIM + DINNER + DSTATE;
    f32x4 sac[4] = {};
    #pragma unroll
    for (int kb=0;kb<4;kb++){
      bf16x8 afr = *(const bf16x8*)(Crow + kb*32 + kq);
      #pragma unroll
      for (int j=0;j<4;j++){
        const ushort* Brow = xcv + (size_t)(c0 + 16*j + l15)*CONVDIM + DINNER;
        bf16x8 bfr = *(const bf16x8*)(Brow + kb*32 + kq);
        sac[j] = __builtin_amdgcn_mfma_f32_16x16x32_bf16(afr, bfr, sac[j], 0,0,0);
      }
    }
    #pragma unroll
    for (int j=0;j<4;j++){
      int s = 16*j + l15;
      float lgs = lg[s], dtss = dts[s];
      #pragma unroll
      for (int r=0;r<4;r++){
        int t = 16*w + quad*4 + r;
        float val = (t >= s) ? sac[j][r]*__expf(lg[t]-lgs)*dtss : 0.f;
        Ps[t*72 + s] = f2bf(val);
      }
    }
  }
  __syncthreads();
  // y tiles (wave w -> p-tile w)
  {
    const float dph = Dp[h];
    bf16x8 hb[4], xb[2];
    const ushort* hrow = hinit + ((size_t)h*NC + c)*8192 + (16*w + l15)*128;
    #pragma unroll
    for (int kb=0;kb<4;kb++) hb[kb] = *(const bf16x8*)(hrow + kb*32 + kq);
    #pragma unroll
    for (int kb=0;kb<2;kb++) xb[kb] = *(const bf16x8*)(XT + (16*w + l15)*72 + kb*32 + kq);
    #pragma unroll
    for (int i=0;i<4;i++){
      const ushort* Crow = xcv + (size_t)(c0 + 16*i + l15)*CONVDIM + DINNER + DSTATE;
      f32x4 y2 = {};
      #pragma unroll
      for (int kb=0;kb<4;kb++){
        bf16x8 afr = *(const bf16x8*)(Crow + kb*32 + kq);
        y2 = __builtin_amdgcn_mfma_f32_16x16x32_bf16(afr, hb[kb], y2, 0,0,0);
      }
      f32x4 y1 = {};
      #pragma unroll
      for (int kb=0;kb<2;kb++){
        bf16x8 afr = *(const bf16x8*)(Ps + (16*i + l15)*72 + kb*32 + kq);
        y1 = __builtin_amdgcn_mfma_f32_16x16x32_bf16(afr, xb[kb], y1, 0,0,0);
      }
      int p = 16*w + l15;
      #pragma unroll
      for (int r=0;r<4;r++){
        int t = 16*i + quad*4 + r;
        float xv = bf2f(XT[p*72 + t]);
        float yv = y1[r] + els[t]*y2[r] + dph*xv;
        yb[(size_t)(c0 + t)*DINNER + h*64 + p] = f2bf(yv);
      }
    }
  }
}

// ---- y(bf16) *= silu(z); RMSNorm(2048) * norm_w -> yg (bf16) ----
__global__ __launch_bounds__(256) void gate_norm_f32(const ushort* __restrict__ yb,
    const float* __restrict__ zx, const float* __restrict__ nw,
    ushort* __restrict__ yg){
  int lr = blockIdx.x, tid = threadIdx.x;
  int d0 = tid*8;
  const ushort* yrow = yb + (size_t)lr*DINNER;
  const float* zrow = zx + (size_t)(lr+3)*NPAD;
  float y[8]; float ss = 0.f;
  #pragma unroll
  for (int i=0;i<8;i++){
    float z = zrow[d0+i];
    float g = z / (1.f + expf(-z));
    float v = bf2f(yrow[d0+i]) * g;
    y[i] = v; ss += v*v;
  }
  #pragma unroll
  for (int m=1;m<64;m<<=1) ss += __shfl_xor(ss, m);
  __shared__ float red[4];
  if ((tid & 63) == 0) red[tid>>6] = ss;
  __syncthreads();
  ss = red[0]+red[1]+red[2]+red[3];
  float scale = rsqrtf(ss * (1.f/DINNER) + 1e-5f);
  ushort* out = yg + (size_t)lr*DINNER;
  #pragma unroll
  for (int i=0;i<8;i++)
    out[d0+i] = f2bf(y[i] * scale * nw[d0+i]);
}

extern "C" void kernel_launch(void* const* d_in, const int* in_sizes, int n_in,
                              void* d_out, int out_size, void* d_ws, size_t ws_size,
                              hipStream_t stream) {
  const float* x    = (const float*)d_in[0];
  const float* ipw  = (const float*)d_in[1];
  const float* cw   = (const float*)d_in[2];
  const float* cb   = (const float*)d_in[3];
  const float* dtb  = (const float*)d_in[4];
  const float* alog = (const float*)d_in[5];
  const float* Dp   = (const float*)d_in[6];
  const float* nw   = (const float*)d_in[7];
  const float* opw  = (const float*)d_in[8];
  char* ws = (char*)d_ws;
  size_t off = 0;
  ushort* xbf    = (ushort*)(ws + off); off += (size_t)ROWS*DMODEL*2;      // 16.8 MB
  ushort* Wp     = (ushort*)(ws + off); off += (size_t)NPAD*DMODEL*2;      //  9.2 MB
  ushort* opwb   = (ushort*)(ws + off); off += (size_t)DMODEL*DINNER*2;    //  4.2 MB
  float*  zxb    = (float*)(ws + off);  off += (size_t)CR*NPAD*4;          // 20.6 MB
  ushort* xconv  = (ushort*)(ws + off); off += (size_t)CL*CONVDIM*2;       //  4.7 MB
  float*  dtv    = (float*)(ws + off);  off += (size_t)CL*NHEADS*4;        //  0.13 MB
  float*  lav    = (float*)(ws + off);  off += (size_t)CL*NHEADS*4;        //  0.13 MB
  ushort* yb     = (ushort*)(ws + off); off += (size_t)CL*DINNER*2;        //  4.2 MB
  ushort* yg     = (ushort*)(ws + off); off += (size_t)CL*DINNER*2;        //  4.2 MB
  ushort* gbuf   = (ushort*)(ws + off); off += (size_t)NHEADS*NC*8192*2;   //  8.4 MB
  ushort* hinit  = (ushort*)(ws + off); off += (size_t)NHEADS*NC*8192*2;   //  8.4 MB
  float*  lgbuf  = (float*)(ws + off);  off += (size_t)NHEADS*NC*Q*4;      //  0.13 MB
  float*  hstate = (float*)(ws + off);  off += (size_t)2*NHEADS*8192*4;    //  2.1 MB
  // total ~83 MB

  cvt_k<<<ROWS*DMODEL/8/256, 256, 0, stream>>>((const float4*)x, (uint4*)xbf);
  padw_cvt<<<NPAD, 256, 0, stream>>>((const float4*)ipw, (ushort4*)Wp);
  cvt_k<<<DMODEL*DINNER/8/256, 256, 0, stream>>>((const float4*)opw, (uint4*)opwb);

  for (int ck = 0; ck < 8; ck++){
    int b  = ck >> 2;
    int l0 = (ck & 3) * CL;
    long grow0 = (long)b*LL + l0 - 3;
    gemm_bt<<<dim3(NPAD/128, CR/128), 256, 0, stream>>>(
        xbf, DMODEL, grow0, (long)ROWS-1, Wp, zxb, NPAD, DMODEL);
    conv_act<<<dim3(CONVDIM/256, CL), 256, 0, stream>>>(zxb, cw, cb, xconv, l0);
    dt_f32<<<CL*NHEADS/256, 256, 0, stream>>>(zxb, dtb, alog, dtv, lav);
    scan_pre<<<dim3(NC, NHEADS), 256, 0, stream>>>(xconv, dtv, lav, gbuf, lgbuf);
    scan_carry<<<NHEADS, 256, 0, stream>>>(gbuf, lgbuf, hinit, hstate, b, (l0==0)?1:0);
    scan_y<<<dim3(NC, NHEADS), 256, 0, stream>>>(xconv, dtv, lgbuf, hinit, Dp, yb);
    gate_norm_f32<<<CL, 256, 0, stream>>>(yb, zxb, nw, yg);
    gemm_bt<<<dim3(DMODEL/128, CL/128), 256, 0, stream>>>(
        yg, DINNER, 0, (long)CL-1, opwb,
        (float*)d_out + (size_t)(b*LL + l0)*DMODEL, DMODEL, DINNER);
  }
}